// Round 11
// baseline (816.228 us; speedup 1.0000x reference)
//
#include <hip/hip_runtime.h>
#include <hip/hip_bf16.h>

typedef unsigned short u16;
typedef __attribute__((ext_vector_type(4))) float f32x4;
typedef __attribute__((ext_vector_type(8))) short bf16x8;

// ---------------------------------------------------------------------------
// helpers
// ---------------------------------------------------------------------------
__device__ __forceinline__ u16 f2bf(float f) {
    union { float f; unsigned u; } v; v.f = f;
    unsigned r = (v.u + 0x7fffu + ((v.u >> 16) & 1u)) >> 16;   // RNE
    return (u16)r;
}

__device__ __forceinline__ float softplus(float x) {
    return (x > 15.f) ? x : log1pf(__expf(x));
}

__device__ __forceinline__ void gload_lds16(const void* g, void* l) {
    __builtin_amdgcn_global_load_lds(
        (__attribute__((address_space(1))) void*)(g),
        (__attribute__((address_space(3))) void*)(l),
        16, 0, 0);
}

#define BAR() do { asm volatile("" ::: "memory"); \
                   __builtin_amdgcn_s_barrier();  \
                   asm volatile("" ::: "memory"); } while (0)

#define DSR(dst, base, off) \
    asm volatile("ds_read_b128 %0, %1 offset:%2" : "=v"(dst) : "v"(base), "i"(off))

#define LGKM0() do { \
    asm volatile("s_waitcnt lgkmcnt(0)" ::: "memory"); \
    __builtin_amdgcn_sched_barrier(0); } while (0)

// ---------------------------------------------------------------------------
// fused prep: x->bf16, W = mu + softplus(rho)*eps -> bf16, bias (f32)
// ---------------------------------------------------------------------------
__global__ __launch_bounds__(256) void prep_all(
        const float* __restrict__ x,
        const float* __restrict__ wmu, const float* __restrict__ wrho,
        const float* __restrict__ ew,
        const float* __restrict__ bmu, const float* __restrict__ brho,
        const float* __restrict__ eb,
        u16* __restrict__ xb, u16* __restrict__ wb, float* __restrict__ bs,
        int nx4, int nw4, int nb) {
    int i = blockIdx.x * 256 + threadIdx.x;
    if (i < nx4) {
        float4 v = ((const float4*)x)[i];
        ushort4 o;
        o.x = f2bf(v.x); o.y = f2bf(v.y); o.z = f2bf(v.z); o.w = f2bf(v.w);
        ((ushort4*)xb)[i] = o;
    }
    if (i < nw4) {
        float4 m = ((const float4*)wmu)[i];
        float4 r = ((const float4*)wrho)[i];
        float4 e = ((const float4*)ew)[i];
        ushort4 o;
        o.x = f2bf(m.x + softplus(r.x) * e.x);
        o.y = f2bf(m.y + softplus(r.y) * e.y);
        o.z = f2bf(m.z + softplus(r.z) * e.z);
        o.w = f2bf(m.w + softplus(r.w) * e.w);
        ((ushort4*)wb)[i] = o;
    }
    if (i < nb) {
        bs[i] = bmu[i] + softplus(brho[i]) * eb[i];
    }
}

// ---------------------------------------------------------------------------
// 128x128 tile / 256-thread / 2-blocks-per-CU bf16 GEMM (B^T) + bias.
// Full register double-buffer of fragments: per tile-set 16 bf16x8
// (a[4][2], b[4][2]); ALL 16 ds_reads for a set issue at PH4/PH8 right after
// the vmcnt(4)-verified barrier and drain under the MFMA cluster — phases
// 1-3/5-7 have no LDS reads. 2 independent blocks/CU give each SIMD two
// unsynchronized waves so one block's barrier/read window fills under the
// other's MFMA. One barrier per phase (wait-before-barrier makes cross-wave
// DMA visibility sound; max skew 1 phase, all write-vs-read pairs disjoint).
// LDS 64 KiB: A0|B0|A1|B1 @ 0|16K|32K|48K, [128][64] bf16 each,
// chunk-XOR swizzle kc ^= row&7 (proven 0-conflict). vmcnt(4) at PH4/PH8.
// ---------------------------------------------------------------------------
template <int MB, int NB>
__device__ __forceinline__ void quad8(f32x4 (&acc)[4][4],
                                      const bf16x8 (&av)[4][2],
                                      const bf16x8 (&bv)[4][2]) {
#pragma unroll
    for (int ks = 0; ks < 2; ++ks)
#pragma unroll
        for (int mi = 0; mi < 2; ++mi)
#pragma unroll
            for (int ni = 0; ni < 2; ++ni)
                acc[MB + mi][NB + ni] = __builtin_amdgcn_mfma_f32_16x16x32_bf16(
                    av[MB + mi][ks], bv[NB + ni][ks], acc[MB + mi][NB + ni], 0, 0, 0);
}

// stage one 64-row half (8 KiB): 2 x global_load_lds(16B) per thread
#define STAGE(regionC, h, P, koff) do {                                         \
    gload_lds16(P[h][0] + (koff), (regionC) + (h) * 8192 + (w * 2 + 0) * 1024); \
    gload_lds16(P[h][1] + (koff), (regionC) + (h) * 8192 + (w * 2 + 1) * 1024); \
} while (0)

// read one full tile-set (16 x ds_read_b128): a[4][2] + b[4][2]
#define RD_TILE(af, bf, R) do {                                        \
    unsigned _a0 = aB0 + (R), _a1 = aB1 + (R);                         \
    unsigned _b0 = bB0 + (R), _b1 = bB1 + (R);                         \
    DSR(bf[0][0], _b0, 0);    DSR(bf[1][0], _b0, 2048);                \
    DSR(bf[0][1], _b1, 0);    DSR(bf[1][1], _b1, 2048);                \
    DSR(af[0][0], _a0, 0);    DSR(af[1][0], _a0, 2048);                \
    DSR(af[0][1], _a1, 0);    DSR(af[1][1], _a1, 2048);                \
    DSR(bf[2][0], _b0, 4096); DSR(bf[3][0], _b0, 6144);                \
    DSR(bf[2][1], _b1, 4096); DSR(bf[3][1], _b1, 6144);                \
    DSR(af[2][0], _a0, 4096); DSR(af[3][0], _a0, 6144);                \
    DSR(af[2][1], _a1, 4096); DSR(af[3][1], _a1, 6144); } while (0)

__global__ __launch_bounds__(256, 2) void gemm128_fr(
        const u16* __restrict__ A,   // [M][K] bf16
        const u16* __restrict__ B,   // [Nout][K] bf16
        const float* __restrict__ bias,
        float* __restrict__ C,       // [M][Nout] fp32
        int M, int Nout, int K) {
    __shared__ __attribute__((aligned(16))) u16 smem[4][8192];  // A0,B0,A1,B1

    const int tid  = threadIdx.x;
    const int lane = tid & 63;
    const int w    = tid >> 6;     // wave 0..3
    const int wr   = w >> 1;       // 0..1 -> 64-row slice
    const int wc   = w & 1;        // 0..1 -> 64-col slice

    char* RA0 = (char*)smem;            // 16 KiB [128][64] bf16
    char* RB0 = (char*)smem + 16384;
    char* RA1 = (char*)smem + 32768;
    char* RB1 = (char*)smem + 49152;

    // bijective XCD swizzle (nwg = 4096, %8 == 0)
    const int nbn = Nout >> 7;                  // 32
    const int nwg = (M >> 7) * nbn;             // 4096
    const int cpx = nwg >> 3;
    const int swz = ((int)blockIdx.x & 7) * cpx + ((int)blockIdx.x >> 3);
    const int m0 = (swz / nbn) << 7;
    const int n0 = (swz % nbn) << 7;

    // per-thread staging source pointers (inverse-swizzled global chunks)
    const u16* PA[2][2]; const u16* PB[2][2];
#pragma unroll
    for (int q = 0; q < 2; ++q) {
        int c   = (w * 2 + q) * 64 + lane;
        int row = c >> 3;                       // 0..63 within half
        int kc  = (c & 7) ^ (row & 7);
#pragma unroll
        for (int h = 0; h < 2; ++h) {
            PA[h][q] = A + (size_t)(m0 + h * 64 + row) * K + kc * 8;
            PB[h][q] = B + (size_t)(n0 + h * 64 + row) * K + kc * 8;
        }
    }

    // fragment-read base addresses (row = r0 + lane&15, r0 multiple of 16;
    // kc(ks) = (ks*4 + lane>>4) ^ (lane&7); byte = row*128 + kc*16)
    const unsigned sb    = (unsigned)(size_t)(void*)&smem[0][0];
    const unsigned loff0 = (unsigned)((lane & 15) * 128 + (((lane >> 4) ^ (lane & 7)) & 7) * 16);
    const unsigned loff1 = (unsigned)((lane & 15) * 128 + ((((lane >> 4) + 4) ^ (lane & 7)) & 7) * 16);
    const unsigned aB0 = sb + (unsigned)(wr * 64 * 128) + loff0;
    const unsigned aB1 = sb + (unsigned)(wr * 64 * 128) + loff1;
    const unsigned bB0 = sb + 16384u + (unsigned)(wc * 64 * 128) + loff0;
    const unsigned bB1 = sb + 16384u + (unsigned)(wc * 64 * 128) + loff1;

    bf16x8 a0f[4][2], b0f[4][2], a1f[4][2], b1f[4][2];
    f32x4 acc[4][4] = {};

    const int NT = K >> 6;    // 64 K-tiles
    const int NI = NT >> 1;   // 32 iterations (2 tiles each)

    // prologue: tile0 -> buf0 (B0,A0), tile1 -> B1.  12 DMA ops; vmcnt(4)
    // retires the 8 oldest (= all of tile0) -> safe to read set0.
    STAGE(RB0, 0, PB, 0);  STAGE(RB0, 1, PB, 0);
    STAGE(RA0, 0, PA, 0);  STAGE(RA0, 1, PA, 0);
    STAGE(RB1, 0, PB, 64); STAGE(RB1, 1, PB, 64);
    asm volatile("s_waitcnt vmcnt(4)" ::: "memory");
    BAR();
    RD_TILE(a0f, b0f, 0);

#pragma unroll 1
    for (int i = 0; i < NI; ++i) {
        int t2 = 2 * i + 2; if (t2 >= NT) t2 -= NT;
        int t3 = 2 * i + 3; if (t3 >= NT) t3 -= NT;
        const int k1 = (2 * i + 1) << 6;
        const int k2 = t2 << 6;
        const int k3 = t3 << 6;

        // ---- PH1: q0 = a-lo x b-lo (set0) | stage A1-lo(t1)
        STAGE(RA1, 0, PA, k1);
        BAR();
        LGKM0();                       // set0 reads (issued PH8/prologue) done
        __builtin_amdgcn_s_setprio(1);
        quad8<0, 0>(acc, a0f, b0f);
        __builtin_amdgcn_s_setprio(0);

        // ---- PH2: q1 = a-lo x b-hi | stage A1-hi(t1)
        STAGE(RA1, 1, PA, k1);
        BAR();
        __builtin_amdgcn_s_setprio(1);
        quad8<0, 2>(acc, a0f, b0f);
        __builtin_amdgcn_s_setprio(0);

        // ---- PH3: q2 = a-hi x b-hi | stage B0-lo(t2)
        STAGE(RB0, 0, PB, k2);
        BAR();
        __builtin_amdgcn_s_setprio(1);
        quad8<2, 2>(acc, a0f, b0f);
        __builtin_amdgcn_s_setprio(0);

        // ---- PH4: q3 = a-hi x b-lo | stage B0-hi(t2) | vmcnt(4): t1 landed
        //      (wait BEFORE barrier => cross-wave DMA visible) then burst-read
        //      set1 (16 ds_reads drain under q3 + following phases)
        STAGE(RB0, 1, PB, k2);
        asm volatile("s_waitcnt vmcnt(4)" ::: "memory");
        BAR();
        RD_TILE(a1f, b1f, 32768);
        __builtin_amdgcn_sched_barrier(0);
        __builtin_amdgcn_s_setprio(1);
        quad8<2, 0>(acc, a0f, b0f);
        __builtin_amdgcn_s_setprio(0);

        // ---- PH5: q0' (set1) | stage A0-lo(t2)
        STAGE(RA0, 0, PA, k2);
        BAR();
        LGKM0();                       // set1 reads done
        __builtin_amdgcn_s_setprio(1);
        quad8<0, 0>(acc, a1f, b1f);
        __builtin_amdgcn_s_setprio(0);

        // ---- PH6: q1' | stage A0-hi(t2)
        STAGE(RA0, 1, PA, k2);
        BAR();
        __builtin_amdgcn_s_setprio(1);
        quad8<0, 2>(acc, a1f, b1f);
        __builtin_amdgcn_s_setprio(0);

        // ---- PH7: q2' | stage B1-lo(t3)
        STAGE(RB1, 0, PB, k3);
        BAR();
        __builtin_amdgcn_s_setprio(1);
        quad8<2, 2>(acc, a1f, b1f);
        __builtin_amdgcn_s_setprio(0);

        // ---- PH8: q3' | stage B1-hi(t3) | vmcnt(4): t2 landed; burst-read
        //      set0 (t2) for next PH1
        STAGE(RB1, 1, PB, k3);
        asm volatile("s_waitcnt vmcnt(4)" ::: "memory");
        BAR();
        RD_TILE(a0f, b0f, 0);
        __builtin_amdgcn_sched_barrier(0);
        __builtin_amdgcn_s_setprio(1);
        quad8<2, 0>(acc, a1f, b1f);
        __builtin_amdgcn_s_setprio(0);
    }

    asm volatile("s_waitcnt vmcnt(0) lgkmcnt(0)" ::: "memory");  // drain

    // epilogue: C/D layout col = lane&15, row = (lane>>4)*4 + q
    const int crow = (lane >> 4) * 4;
    const int ccol = lane & 15;
#pragma unroll
    for (int mi = 0; mi < 4; ++mi) {
#pragma unroll
        for (int ni = 0; ni < 4; ++ni) {
            const int row = m0 + wr * 64 + mi * 16 + crow;
            const int col = n0 + wc * 64 + ni * 16 + ccol;
            const float bv = bias[col];
            float* Cp = C + (size_t)row * Nout + col;
#pragma unroll
            for (int q = 0; q < 4; ++q)
                Cp[(size_t)q * Nout] = acc[mi][ni][q] + bv;
        }
    }
}

// ---------------------------------------------------------------------------
// launch
// ---------------------------------------------------------------------------
extern "C" void kernel_launch(void* const* d_in, const int* in_sizes, int n_in,
                              void* d_out, int out_size, void* d_ws, size_t ws_size,
                              hipStream_t stream) {
    const float* x    = (const float*)d_in[0];
    const float* wmu  = (const float*)d_in[1];
    const float* wrho = (const float*)d_in[2];
    const float* bmu  = (const float*)d_in[3];
    const float* brho = (const float*)d_in[4];
    const float* ew   = (const float*)d_in[5];
    const float* eb   = (const float*)d_in[6];
    float* out = (float*)d_out;

    const int Nout = in_sizes[3];            // 4096
    const int K    = in_sizes[1] / Nout;     // 4096
    const int M    = in_sizes[0] / K;        // 16384

    u16* xb = (u16*)d_ws;
    u16* wb = xb + (size_t)M * K;
    float* bs = (float*)(wb + (size_t)Nout * K);

    const int nx4 = (M * K) / 4;
    const int nw4 = (Nout * K) / 4;
    prep_all<<<(nx4 + 255) / 256, 256, 0, stream>>>(
        x, wmu, wrho, ew, bmu, brho, eb, xb, wb, bs, nx4, nw4, Nout);

    dim3 grid((M / 128) * (Nout / 128));
    gemm128_fr<<<grid, 256, 0, stream>>>(xb, wb, bs, out, M, Nout, K);
}

// Round 12
// 586.012 us; speedup vs baseline: 1.3929x; 1.3929x over previous
//
#include <hip/hip_runtime.h>
#include <hip/hip_bf16.h>

typedef unsigned short u16;
typedef __attribute__((ext_vector_type(4))) float f32x4;
typedef __attribute__((ext_vector_type(8))) short bf16x8;

// ---------------------------------------------------------------------------
// helpers
// ---------------------------------------------------------------------------
__device__ __forceinline__ u16 f2bf(float f) {
    union { float f; unsigned u; } v; v.f = f;
    unsigned r = (v.u + 0x7fffu + ((v.u >> 16) & 1u)) >> 16;   // RNE
    return (u16)r;
}

__device__ __forceinline__ float softplus(float x) {
    return (x > 15.f) ? x : log1pf(__expf(x));
}

__device__ __forceinline__ void gload_lds16(const void* g, void* l) {
    __builtin_amdgcn_global_load_lds(
        (__attribute__((address_space(1))) void*)(g),
        (__attribute__((address_space(3))) void*)(l),
        16, 0, 0);
}

#define BAR() do { asm volatile("" ::: "memory"); \
                   __builtin_amdgcn_s_barrier();  \
                   asm volatile("" ::: "memory"); } while (0)

// non-temporal scalar store: C lines are never re-read; keep them out of L2/L3
// so A/B panels stay resident (staged-load latency L3 vs HBM).
#define ST_NT(addr, val) \
    asm volatile("global_store_dword %0, %1, off nt" :: "v"(addr), "v"(val) : "memory")

// ---------------------------------------------------------------------------
// fused prep: x->bf16, W = mu + softplus(rho)*eps -> bf16, bias (f32)
// ---------------------------------------------------------------------------
__global__ __launch_bounds__(256) void prep_all(
        const float* __restrict__ x,
        const float* __restrict__ wmu, const float* __restrict__ wrho,
        const float* __restrict__ ew,
        const float* __restrict__ bmu, const float* __restrict__ brho,
        const float* __restrict__ eb,
        u16* __restrict__ xb, u16* __restrict__ wb, float* __restrict__ bs,
        int nx4, int nw4, int nb) {
    int i = blockIdx.x * 256 + threadIdx.x;
    if (i < nx4) {
        float4 v = ((const float4*)x)[i];
        ushort4 o;
        o.x = f2bf(v.x); o.y = f2bf(v.y); o.z = f2bf(v.z); o.w = f2bf(v.w);
        ((ushort4*)xb)[i] = o;
    }
    if (i < nw4) {
        float4 m = ((const float4*)wmu)[i];
        float4 r = ((const float4*)wrho)[i];
        float4 e = ((const float4*)ew)[i];
        ushort4 o;
        o.x = f2bf(m.x + softplus(r.x) * e.x);
        o.y = f2bf(m.y + softplus(r.y) * e.y);
        o.z = f2bf(m.z + softplus(r.z) * e.z);
        o.w = f2bf(m.w + softplus(r.w) * e.w);
        ((ushort4*)wb)[i] = o;
    }
    if (i < nb) {
        bs[i] = bmu[i] + softplus(brho[i]) * eb[i];
    }
}

// ---------------------------------------------------------------------------
// 256x256 8-phase bf16 GEMM (B^T) + bias — round-3 schedule verbatim
// (best measured: 477 us GEMM, 0 bank conflicts) + nt epilogue stores.
// LDS: 2 dbuf x {A,B} x [256][64] bf16, chunk-XOR swizzle kc ^= row&7;
// reads 4/4/8/8 per phase; vmcnt(4) at PH4/PH8.
// ---------------------------------------------------------------------------
__device__ __forceinline__ bf16x8 ld_frag(const u16* region, int r0, int ks, int lane) {
    int row = r0 + (lane & 15);
    int kc  = (ks * 4 + (lane >> 4)) ^ (row & 7);
    return *(const bf16x8*)((const char*)region + row * 128 + kc * 16);
}

template <int MB, int NB>
__device__ __forceinline__ void mfma_quad(f32x4 (&acc)[8][4],
                                          const bf16x8 (&av)[4][2],
                                          const bf16x8 (&bv)[2][2]) {
#pragma unroll
    for (int ks = 0; ks < 2; ++ks)
#pragma unroll
        for (int mi = 0; mi < 4; ++mi)
#pragma unroll
            for (int ni = 0; ni < 2; ++ni)
                acc[MB + mi][NB + ni] = __builtin_amdgcn_mfma_f32_16x16x32_bf16(
                    av[mi][ks], bv[ni][ks], acc[MB + mi][NB + ni], 0, 0, 0);
}

#define STAGE(region, h, P, koff) do {                                          \
    gload_lds16(P[h][0] + (koff), (char*)(region) + (h) * 16384 + (w * 2 + 0) * 1024); \
    gload_lds16(P[h][1] + (koff), (char*)(region) + (h) * 16384 + (w * 2 + 1) * 1024); \
} while (0)

#define RD_A(reg, roff)                                                \
    _Pragma("unroll")                                                  \
    for (int mi = 0; mi < 4; ++mi)                                     \
        _Pragma("unroll")                                              \
        for (int ks = 0; ks < 2; ++ks)                                 \
            a[mi][ks] = ld_frag(reg, wr * 128 + (roff) + mi * 16, ks, lane)

#define RD_B(dst, reg, roff)                                           \
    _Pragma("unroll")                                                  \
    for (int ni = 0; ni < 2; ++ni)                                     \
        _Pragma("unroll")                                              \
        for (int ks = 0; ks < 2; ++ks)                                 \
            dst[ni][ks] = ld_frag(reg, wc * 64 + (roff) + ni * 16, ks, lane)

__global__ __launch_bounds__(512, 2) void gemm256_8ph(
        const u16* __restrict__ A,   // [M][K] bf16
        const u16* __restrict__ B,   // [Nout][K] bf16
        const float* __restrict__ bias,
        float* __restrict__ C,       // [M][Nout] fp32
        int M, int Nout, int K) {
    __shared__ __attribute__((aligned(16))) u16 smem[4][16384];  // A0,B0,A1,B1
    u16* A0 = smem[0]; u16* B0 = smem[1];
    u16* A1 = smem[2]; u16* B1 = smem[3];

    const int tid  = threadIdx.x;
    const int lane = tid & 63;
    const int w    = tid >> 6;     // wave 0..7
    const int wr   = w >> 2;       // 0..1 -> 128-row slice
    const int wc   = w & 3;        // 0..3 -> 64-col slice

    // bijective XCD swizzle (nwg % 8 == 0 here)
    const int nbn = Nout >> 8;
    const int nwg = (M >> 8) * nbn;
    const int cpx = nwg >> 3;
    const int swz = ((int)blockIdx.x & 7) * cpx + ((int)blockIdx.x >> 3);
    const int m0 = (swz / nbn) << 8;
    const int n0 = (swz % nbn) << 8;

    // per-thread staging source pointers (inverse-swizzled global chunks)
    const u16* PA[2][2]; const u16* PB[2][2];
#pragma unroll
    for (int q = 0; q < 2; ++q) {
        int c   = (w * 2 + q) * 64 + lane;
        int row = c >> 3;
        int kc  = (c & 7) ^ (row & 7);
#pragma unroll
        for (int h = 0; h < 2; ++h) {
            PA[h][q] = A + (size_t)(m0 + h * 128 + row) * K + kc * 8;
            PB[h][q] = B + (size_t)(n0 + h * 128 + row) * K + kc * 8;
        }
    }

    bf16x8 a[4][2], bl[2][2], bh[2][2];
    f32x4 acc[8][4] = {};

    const int NT = K >> 6;    // K-tiles
    const int NI = NT >> 1;   // iterations (2 tiles each)

    // prologue: tile0 -> buf0 (all), tile1 -> buf1 (B units)
    STAGE(B0, 0, PB, 0);  STAGE(B0, 1, PB, 0);
    STAGE(A0, 0, PA, 0);  STAGE(A0, 1, PA, 0);
    STAGE(B1, 0, PB, 64); STAGE(B1, 1, PB, 64);
    asm volatile("s_waitcnt vmcnt(4)" ::: "memory");   // tile0 landed
    BAR();
    RD_A(A0, 0);   // al pre-read for PH1 (matches PH8-exit state)

#pragma unroll 1
    for (int i = 0; i < NI; ++i) {
        int t2 = 2 * i + 2; if (t2 >= NT) t2 -= NT;
        int t3 = 2 * i + 3; if (t3 >= NT) t3 -= NT;
        const int k1 = (2 * i + 1) << 6;
        const int k2 = t2 << 6;
        const int k3 = t3 << 6;

        // -------- PH1: q0 = al x bl          | reads bl(4) | stage A1-lo(t1)
        RD_B(bl, B0, 0);
        STAGE(A1, 0, PA, k1);
        BAR();
        asm volatile("s_waitcnt lgkmcnt(0)" ::: "memory");
        __builtin_amdgcn_s_setprio(1);
        mfma_quad<0, 0>(acc, a, bl);
        __builtin_amdgcn_s_setprio(0);
        BAR();

        // -------- PH2: q1 = al x bh          | reads bh(4) | stage A1-hi(t1)
        RD_B(bh, B0, 32);
        STAGE(A1, 1, PA, k1);
        BAR();
        asm volatile("s_waitcnt lgkmcnt(0)" ::: "memory");
        __builtin_amdgcn_s_setprio(1);
        mfma_quad<0, 2>(acc, a, bh);
        __builtin_amdgcn_s_setprio(0);
        BAR();

        // -------- PH3: q2 = ah x bh          | reads ah(8) | stage B0-lo(t2)
        RD_A(A0, 64);
        STAGE(B0, 0, PB, k2);
        BAR();
        asm volatile("s_waitcnt lgkmcnt(0)" ::: "memory");
        __builtin_amdgcn_s_setprio(1);
        mfma_quad<4, 2>(acc, a, bh);
        __builtin_amdgcn_s_setprio(0);
        BAR();

        // -------- PH4: q3 = ah x bl | stage B0-hi(t2) | vmcnt(4): t1 landed
        //          then read al'(8) from A1 (hidden under q3's MFMA drain)
        STAGE(B0, 1, PB, k2);
        asm volatile("s_waitcnt vmcnt(4)" ::: "memory");
        BAR();
        __builtin_amdgcn_s_setprio(1);
        mfma_quad<4, 0>(acc, a, bl);
        __builtin_amdgcn_s_setprio(0);
        RD_A(A1, 0);
        BAR();

        // -------- PH5: q0' = al' x bl'       | reads bl'(4) | stage A0-lo(t2)
        RD_B(bl, B1, 0);
        STAGE(A0, 0, PA, k2);
        BAR();
        asm volatile("s_waitcnt lgkmcnt(0)" ::: "memory");
        __builtin_amdgcn_s_setprio(1);
        mfma_quad<0, 0>(acc, a, bl);
        __builtin_amdgcn_s_setprio(0);
        BAR();

        // -------- PH6: q1' = al' x bh'       | reads bh'(4) | stage A0-hi(t2)
        RD_B(bh, B1, 32);
        STAGE(A0, 1, PA, k2);
        BAR();
        asm volatile("s_waitcnt lgkmcnt(0)" ::: "memory");
        __builtin_amdgcn_s_setprio(1);
        mfma_quad<0, 2>(acc, a, bh);
        __builtin_amdgcn_s_setprio(0);
        BAR();

        // -------- PH7: q2' = ah' x bh'       | reads ah'(8) | stage B1-lo(t3)
        RD_A(A1, 64);
        STAGE(B1, 0, PB, k3);
        BAR();
        asm volatile("s_waitcnt lgkmcnt(0)" ::: "memory");
        __builtin_amdgcn_s_setprio(1);
        mfma_quad<4, 2>(acc, a, bh);
        __builtin_amdgcn_s_setprio(0);
        BAR();

        // -------- PH8: q3' = ah' x bl' | stage B1-hi(t3) | vmcnt(4): t2 landed
        //          then read al''(8) from A0 for next iteration's PH1
        STAGE(B1, 1, PB, k3);
        asm volatile("s_waitcnt vmcnt(4)" ::: "memory");
        BAR();
        __builtin_amdgcn_s_setprio(1);
        mfma_quad<4, 0>(acc, a, bl);
        __builtin_amdgcn_s_setprio(0);
        RD_A(A0, 0);
        BAR();
    }

    asm volatile("s_waitcnt vmcnt(0)" ::: "memory");  // drain wrapped prefetch

    // epilogue: C/D layout col = lane&15, row = (lane>>4)*4 + q; nt stores
    const int crow = (lane >> 4) * 4;
    const int ccol = lane & 15;
#pragma unroll
    for (int mi = 0; mi < 8; ++mi) {
#pragma unroll
        for (int ni = 0; ni < 4; ++ni) {
            const int row = m0 + wr * 128 + mi * 16 + crow;
            const int col = n0 + wc * 64 + ni * 16 + ccol;
            const float bv = bias[col];
            float* Cp = C + (size_t)row * Nout + col;
#pragma unroll
            for (int q = 0; q < 4; ++q) {
                float v = acc[mi][ni][q] + bv;
                ST_NT(Cp + (size_t)q * Nout, v);
            }
        }
    }
}

// ---------------------------------------------------------------------------
// launch
// ---------------------------------------------------------------------------
extern "C" void kernel_launch(void* const* d_in, const int* in_sizes, int n_in,
                              void* d_out, int out_size, void* d_ws, size_t ws_size,
                              hipStream_t stream) {
    const float* x    = (const float*)d_in[0];
    const float* wmu  = (const float*)d_in[1];
    const float* wrho = (const float*)d_in[2];
    const float* bmu  = (const float*)d_in[3];
    const float* brho = (const float*)d_in[4];
    const float* ew   = (const float*)d_in[5];
    const float* eb   = (const float*)d_in[6];
    float* out = (float*)d_out;

    const int Nout = in_sizes[3];            // 4096
    const int K    = in_sizes[1] / Nout;     // 4096
    const int M    = in_sizes[0] / K;        // 16384

    u16* xb = (u16*)d_ws;
    u16* wb = xb + (size_t)M * K;
    float* bs = (float*)(wb + (size_t)Nout * K);

    const int nx4 = (M * K) / 4;
    const int nw4 = (Nout * K) / 4;
    prep_all<<<(nx4 + 255) / 256, 256, 0, stream>>>(
        x, wmu, wrho, ew, bmu, brho, eb, xb, wb, bs, nx4, nw4, Nout);

    dim3 grid((M / 256) * (Nout / 256));
    gemm256_8ph<<<grid, 512, 0, stream>>>(xb, wb, bs, out, M, Nout, K);
}

// Round 13
// 567.995 us; speedup vs baseline: 1.4370x; 1.0317x over previous
//
#include <hip/hip_runtime.h>
#include <hip/hip_bf16.h>

typedef unsigned short u16;
typedef __attribute__((ext_vector_type(4))) float f32x4;
typedef __attribute__((ext_vector_type(8))) short bf16x8;

// ---------------------------------------------------------------------------
// helpers
// ---------------------------------------------------------------------------
__device__ __forceinline__ u16 f2bf(float f) {
    union { float f; unsigned u; } v; v.f = f;
    unsigned r = (v.u + 0x7fffu + ((v.u >> 16) & 1u)) >> 16;   // RNE
    return (u16)r;
}

__device__ __forceinline__ float softplus(float x) {
    return (x > 15.f) ? x : log1pf(__expf(x));
}

__device__ __forceinline__ void gload_lds16(const void* g, void* l) {
    __builtin_amdgcn_global_load_lds(
        (__attribute__((address_space(1))) void*)(g),
        (__attribute__((address_space(3))) void*)(l),
        16, 0, 0);
}

#define BAR() do { asm volatile("" ::: "memory"); \
                   __builtin_amdgcn_s_barrier();  \
                   asm volatile("" ::: "memory"); } while (0)

// ---------------------------------------------------------------------------
// fused prep: x->bf16, W = mu + softplus(rho)*eps -> bf16, bias (f32)
// ---------------------------------------------------------------------------
__global__ __launch_bounds__(256) void prep_all(
        const float* __restrict__ x,
        const float* __restrict__ wmu, const float* __restrict__ wrho,
        const float* __restrict__ ew,
        const float* __restrict__ bmu, const float* __restrict__ brho,
        const float* __restrict__ eb,
        u16* __restrict__ xb, u16* __restrict__ wb, float* __restrict__ bs,
        int nx4, int nw4, int nb) {
    int i = blockIdx.x * 256 + threadIdx.x;
    if (i < nx4) {
        float4 v = ((const float4*)x)[i];
        ushort4 o;
        o.x = f2bf(v.x); o.y = f2bf(v.y); o.z = f2bf(v.z); o.w = f2bf(v.w);
        ((ushort4*)xb)[i] = o;
    }
    if (i < nw4) {
        float4 m = ((const float4*)wmu)[i];
        float4 r = ((const float4*)wrho)[i];
        float4 e = ((const float4*)ew)[i];
        ushort4 o;
        o.x = f2bf(m.x + softplus(r.x) * e.x);
        o.y = f2bf(m.y + softplus(r.y) * e.y);
        o.z = f2bf(m.z + softplus(r.z) * e.z);
        o.w = f2bf(m.w + softplus(r.w) * e.w);
        ((ushort4*)wb)[i] = o;
    }
    if (i < nb) {
        bs[i] = bmu[i] + softplus(brho[i]) * eb[i];
    }
}

// ---------------------------------------------------------------------------
// 256x256 8-phase bf16 GEMM (B^T) + bias — round-3 champion, restored.
// LDS: 2 dbuf x {A,B} x [256][64] bf16, chunk-XOR swizzle kc ^= row&7;
// reads 4/4/8/8 per phase; vmcnt(4) at PH4/PH8; plain dword stores.
// Measured: GEMM ~477 us (1.15 PF, 46% dense peak), MfmaUtil ~55%,
// 0 bank conflicts. Ten structural/micro variants tested (r4-r12): all
// null or negative — this is the converged form.
// ---------------------------------------------------------------------------
__device__ __forceinline__ bf16x8 ld_frag(const u16* region, int r0, int ks, int lane) {
    int row = r0 + (lane & 15);
    int kc  = (ks * 4 + (lane >> 4)) ^ (row & 7);
    return *(const bf16x8*)((const char*)region + row * 128 + kc * 16);
}

template <int MB, int NB>
__device__ __forceinline__ void mfma_quad(f32x4 (&acc)[8][4],
                                          const bf16x8 (&av)[4][2],
                                          const bf16x8 (&bv)[2][2]) {
#pragma unroll
    for (int ks = 0; ks < 2; ++ks)
#pragma unroll
        for (int mi = 0; mi < 4; ++mi)
#pragma unroll
            for (int ni = 0; ni < 2; ++ni)
                acc[MB + mi][NB + ni] = __builtin_amdgcn_mfma_f32_16x16x32_bf16(
                    av[mi][ks], bv[ni][ks], acc[MB + mi][NB + ni], 0, 0, 0);
}

#define STAGE(region, h, P, koff) do {                                          \
    gload_lds16(P[h][0] + (koff), (char*)(region) + (h) * 16384 + (w * 2 + 0) * 1024); \
    gload_lds16(P[h][1] + (koff), (char*)(region) + (h) * 16384 + (w * 2 + 1) * 1024); \
} while (0)

#define RD_A(reg, roff)                                                \
    _Pragma("unroll")                                                  \
    for (int mi = 0; mi < 4; ++mi)                                     \
        _Pragma("unroll")                                              \
        for (int ks = 0; ks < 2; ++ks)                                 \
            a[mi][ks] = ld_frag(reg, wr * 128 + (roff) + mi * 16, ks, lane)

#define RD_B(dst, reg, roff)                                           \
    _Pragma("unroll")                                                  \
    for (int ni = 0; ni < 2; ++ni)                                     \
        _Pragma("unroll")                                              \
        for (int ks = 0; ks < 2; ++ks)                                 \
            dst[ni][ks] = ld_frag(reg, wc * 64 + (roff) + ni * 16, ks, lane)

__global__ __launch_bounds__(512, 2) void gemm256_8ph(
        const u16* __restrict__ A,   // [M][K] bf16
        const u16* __restrict__ B,   // [Nout][K] bf16
        const float* __restrict__ bias,
        float* __restrict__ C,       // [M][Nout] fp32
        int M, int Nout, int K) {
    __shared__ __attribute__((aligned(16))) u16 smem[4][16384];  // A0,B0,A1,B1
    u16* A0 = smem[0]; u16* B0 = smem[1];
    u16* A1 = smem[2]; u16* B1 = smem[3];

    const int tid  = threadIdx.x;
    const int lane = tid & 63;
    const int w    = tid >> 6;     // wave 0..7
    const int wr   = w >> 2;       // 0..1 -> 128-row slice
    const int wc   = w & 3;        // 0..3 -> 64-col slice

    // bijective XCD swizzle (nwg % 8 == 0 here)
    const int nbn = Nout >> 8;
    const int nwg = (M >> 8) * nbn;
    const int cpx = nwg >> 3;
    const int swz = ((int)blockIdx.x & 7) * cpx + ((int)blockIdx.x >> 3);
    const int m0 = (swz / nbn) << 8;
    const int n0 = (swz % nbn) << 8;

    // per-thread staging source pointers (inverse-swizzled global chunks)
    const u16* PA[2][2]; const u16* PB[2][2];
#pragma unroll
    for (int q = 0; q < 2; ++q) {
        int c   = (w * 2 + q) * 64 + lane;
        int row = c >> 3;
        int kc  = (c & 7) ^ (row & 7);
#pragma unroll
        for (int h = 0; h < 2; ++h) {
            PA[h][q] = A + (size_t)(m0 + h * 128 + row) * K + kc * 8;
            PB[h][q] = B + (size_t)(n0 + h * 128 + row) * K + kc * 8;
        }
    }

    bf16x8 a[4][2], bl[2][2], bh[2][2];
    f32x4 acc[8][4] = {};

    const int NT = K >> 6;    // K-tiles
    const int NI = NT >> 1;   // iterations (2 tiles each)

    // prologue: tile0 -> buf0 (all), tile1 -> buf1 (B units)
    STAGE(B0, 0, PB, 0);  STAGE(B0, 1, PB, 0);
    STAGE(A0, 0, PA, 0);  STAGE(A0, 1, PA, 0);
    STAGE(B1, 0, PB, 64); STAGE(B1, 1, PB, 64);
    asm volatile("s_waitcnt vmcnt(4)" ::: "memory");   // tile0 landed
    BAR();
    RD_A(A0, 0);   // al pre-read for PH1 (matches PH8-exit state)

#pragma unroll 1
    for (int i = 0; i < NI; ++i) {
        int t2 = 2 * i + 2; if (t2 >= NT) t2 -= NT;
        int t3 = 2 * i + 3; if (t3 >= NT) t3 -= NT;
        const int k1 = (2 * i + 1) << 6;
        const int k2 = t2 << 6;
        const int k3 = t3 << 6;

        // -------- PH1: q0 = al x bl          | reads bl(4) | stage A1-lo(t1)
        RD_B(bl, B0, 0);
        STAGE(A1, 0, PA, k1);
        BAR();
        asm volatile("s_waitcnt lgkmcnt(0)" ::: "memory");
        __builtin_amdgcn_s_setprio(1);
        mfma_quad<0, 0>(acc, a, bl);
        __builtin_amdgcn_s_setprio(0);
        BAR();

        // -------- PH2: q1 = al x bh          | reads bh(4) | stage A1-hi(t1)
        RD_B(bh, B0, 32);
        STAGE(A1, 1, PA, k1);
        BAR();
        asm volatile("s_waitcnt lgkmcnt(0)" ::: "memory");
        __builtin_amdgcn_s_setprio(1);
        mfma_quad<0, 2>(acc, a, bh);
        __builtin_amdgcn_s_setprio(0);
        BAR();

        // -------- PH3: q2 = ah x bh          | reads ah(8) | stage B0-lo(t2)
        RD_A(A0, 64);
        STAGE(B0, 0, PB, k2);
        BAR();
        asm volatile("s_waitcnt lgkmcnt(0)" ::: "memory");
        __builtin_amdgcn_s_setprio(1);
        mfma_quad<4, 2>(acc, a, bh);
        __builtin_amdgcn_s_setprio(0);
        BAR();

        // -------- PH4: q3 = ah x bl | stage B0-hi(t2) | vmcnt(4): t1 landed
        //          then read al'(8) from A1 (hidden under q3's MFMA drain)
        STAGE(B0, 1, PB, k2);
        asm volatile("s_waitcnt vmcnt(4)" ::: "memory");
        BAR();
        __builtin_amdgcn_s_setprio(1);
        mfma_quad<4, 0>(acc, a, bl);
        __builtin_amdgcn_s_setprio(0);
        RD_A(A1, 0);
        BAR();

        // -------- PH5: q0' = al' x bl'       | reads bl'(4) | stage A0-lo(t2)
        RD_B(bl, B1, 0);
        STAGE(A0, 0, PA, k2);
        BAR();
        asm volatile("s_waitcnt lgkmcnt(0)" ::: "memory");
        __builtin_amdgcn_s_setprio(1);
        mfma_quad<0, 0>(acc, a, bl);
        __builtin_amdgcn_s_setprio(0);
        BAR();

        // -------- PH6: q1' = al' x bh'       | reads bh'(4) | stage A0-hi(t2)
        RD_B(bh, B1, 32);
        STAGE(A0, 1, PA, k2);
        BAR();
        asm volatile("s_waitcnt lgkmcnt(0)" ::: "memory");
        __builtin_amdgcn_s_setprio(1);
        mfma_quad<0, 2>(acc, a, bh);
        __builtin_amdgcn_s_setprio(0);
        BAR();

        // -------- PH7: q2' = ah' x bh'       | reads ah'(8) | stage B1-lo(t3)
        RD_A(A1, 64);
        STAGE(B1, 0, PB, k3);
        BAR();
        asm volatile("s_waitcnt lgkmcnt(0)" ::: "memory");
        __builtin_amdgcn_s_setprio(1);
        mfma_quad<4, 2>(acc, a, bh);
        __builtin_amdgcn_s_setprio(0);
        BAR();

        // -------- PH8: q3' = ah' x bl' | stage B1-hi(t3) | vmcnt(4): t2 landed
        //          then read al''(8) from A0 for next iteration's PH1
        STAGE(B1, 1, PB, k3);
        asm volatile("s_waitcnt vmcnt(4)" ::: "memory");
        BAR();
        __builtin_amdgcn_s_setprio(1);
        mfma_quad<4, 0>(acc, a, bl);
        __builtin_amdgcn_s_setprio(0);
        RD_A(A0, 0);
        BAR();
    }

    asm volatile("s_waitcnt vmcnt(0)" ::: "memory");  // drain wrapped prefetch

    // epilogue: C/D layout col = lane&15, row = (lane>>4)*4 + q
    const int crow = (lane >> 4) * 4;
    const int ccol = lane & 15;
#pragma unroll
    for (int mi = 0; mi < 8; ++mi) {
#pragma unroll
        for (int ni = 0; ni < 4; ++ni) {
            const int row = m0 + wr * 128 + mi * 16 + crow;
            const int col = n0 + wc * 64 + ni * 16 + ccol;
            const float bv = bias[col];
            float* Cp = C + (size_t)row * Nout + col;
#pragma unroll
            for (int q = 0; q < 4; ++q)
                Cp[(size_t)q * Nout] = acc[mi][ni][q] + bv;
        }
    }
}

// ---------------------------------------------------------------------------
// launch
// ---------------------------------------------------------------------------
extern "C" void kernel_launch(void* const* d_in, const int* in_sizes, int n_in,
                              void* d_out, int out_size, void* d_ws, size_t ws_size,
                              hipStream_t stream) {
    const float* x    = (const float*)d_in[0];
    const float* wmu  = (const float*)d_in[1];
    const float* wrho = (const float*)d_in[2];
    const float* bmu  = (const float*)d_in[3];
    const float* brho = (const float*)d_in[4];
    const float* ew   = (const float*)d_in[5];
    const float* eb   = (const float*)d_in[6];
    float* out = (float*)d_out;

    const int Nout = in_sizes[3];            // 4096
    const int K    = in_sizes[1] / Nout;     // 4096
    const int M    = in_sizes[0] / K;        // 16384

    u16* xb = (u16*)d_ws;
    u16* wb = xb + (size_t)M * K;
    float* bs = (float*)(wb + (size_t)Nout * K);

    const int nx4 = (M * K) / 4;
    const int nw4 = (Nout * K) / 4;
    prep_all<<<(nx4 + 255) / 256, 256, 0, stream>>>(
        x, wmu, wrho, ew, bmu, brho, eb, xb, wb, bs, nx4, nw4, Nout);

    dim3 grid((M / 256) * (Nout / 256));
    gemm256_8ph<<<grid, 512, 0, stream>>>(xb, wb, bs, out, M, Nout, K);
}